// Round 13
// baseline (368.599 us; speedup 1.0000x reference)
//
#include <hip/hip_runtime.h>

#define DEVINL __device__ __forceinline__

DEVINL float leaky(float v) { return v >= 0.f ? v : 0.2f * v; }

typedef float v4f __attribute__((ext_vector_type(4)));

DEVINL void nt_store4(float* p, float4 v) {
    v4f q = {v.x, v.y, v.z, v.w};
    __builtin_nontemporal_store(q, (v4f*)p);
}

// bf16 helpers (RNE pack, shift unpack)
DEVINL unsigned short f2bf(float f) {
    unsigned int u = __float_as_uint(f);
    unsigned int r = (u + 0x7FFFu + ((u >> 16) & 1u)) >> 16;
    return (unsigned short)r;
}
DEVINL float bflo(unsigned int u) { return __uint_as_float(u << 16); }
DEVINL float bfhi(unsigned int u) { return __uint_as_float(u & 0xFFFF0000u); }

// ---------------------------------------------------------------------------
// Precompute per-level head projection vectors.
// ---------------------------------------------------------------------------
__global__ void wprep_kernel(const float* __restrict__ lin,   // (6,64,64)
                             const float* __restrict__ asrc,  // (6,4,16)
                             const float* __restrict__ adst,  // (6,4,16)
                             float* __restrict__ w_out) {     // (6,2,4,64)
    int idx = blockIdx.x * blockDim.x + threadIdx.x;
    if (idx >= 6 * 4 * 64) return;
    int c = idx & 63;
    int h = (idx >> 6) & 3;
    int k = idx >> 8;
    const float* L = lin + k * 64 * 64;
    float s1 = 0.f, s2 = 0.f;
    for (int e = 0; e < 16; ++e) {
        float w = L[(h * 16 + e) * 64 + c];
        s1 += w * asrc[(k * 4 + h) * 16 + e];
        s2 += w * adst[(k * 4 + h) * 16 + e];
    }
    w_out[(k * 2 + 0) * 256 + h * 64 + c] = s1;
    w_out[(k * 2 + 1) * 256 + h * 64 + c] = s2;
}

// ---------------------------------------------------------------------------
// Transpose pool weights once.
// ---------------------------------------------------------------------------
__global__ void wtrans_kernel(const float* __restrict__ s0, const float* __restrict__ s1,
                              const float* __restrict__ t0, const float* __restrict__ t1,
                              const float* __restrict__ s0w2, const float* __restrict__ s1w2,
                              const float* __restrict__ t0w2, const float* __restrict__ t1w2,
                              float* __restrict__ o) {
    int idx = blockIdx.x * 256 + threadIdx.x;
    if (idx < 16384) {
        int m = idx >> 12, r = idx & 4095, c = r >> 6, d = r & 63;
        const float* src = (m == 0) ? s0 : (m == 1) ? s1 : (m == 2) ? t0 : t1;
        o[idx] = src[d * 64 + c];
    } else if (idx < 16384 + 768) {
        int j = idx - 16384, c = j / 12, k = j - 12 * c;
        o[idx] = s0w2[k * 64 + c];
    } else if (idx < 17152 + 512) {
        int j = idx - 17152, c = j >> 3, k = j & 7;
        o[idx] = (k < 5) ? s1w2[k * 64 + c] : 0.f;
    } else if (idx < 17664 + 2048) {
        int j = idx - 17664, c = j >> 5, k = j & 31;
        o[idx] = t0w2[k * 64 + c];
    } else if (idx < 19712 + 768) {
        int j = idx - 19712, c = j / 12, k = j - 12 * c;
        o[idx] = t1w2[k * 64 + c];
    }
}

// ---------------------------------------------------------------------------
// Transposes: src (B=64, C=64, T=64, J=25)
// ---------------------------------------------------------------------------
__global__ void xs_kernel(const float* __restrict__ src, float* __restrict__ xs) {
    int g = blockIdx.x;             // b*64 + t
    int b = g >> 6, t = g & 63;
    __shared__ float tile[64][26];  // [c][j]
    const float* sp = src + b * 102400 + t * 25;
    for (int idx = threadIdx.x; idx < 64 * 25; idx += blockDim.x) {
        int c = idx / 25, j = idx - c * 25;
        tile[c][j] = sp[c * 1600 + j];
    }
    __syncthreads();
    float* op = xs + g * 25 * 64;
    for (int idx = threadIdx.x; idx < 25 * 64; idx += blockDim.x) {
        int j = idx >> 6, c = idx & 63;
        op[idx] = tile[c][j];
    }
}

__global__ void xt_kernel(const float* __restrict__ src, float* __restrict__ xt) {
    int g = blockIdx.x;             // b*25 + j
    int b = g / 25, j = g - b * 25;
    __shared__ float tile[64][65];  // [c][t]
    const float* sp = src + b * 102400 + j;
    for (int idx = threadIdx.x; idx < 64 * 64; idx += blockDim.x) {
        int c = idx >> 6, t = idx & 63;
        tile[c][t] = sp[c * 1600 + t * 25];
    }
    __syncthreads();
    float* op = xt + g * 64 * 64;
    for (int idx = threadIdx.x; idx < 64 * 64; idx += blockDim.x) {
        int t = idx >> 6, c = idx & 63;
        op[idx] = tile[c][t];
    }
}

// ---------------------------------------------------------------------------
// GAT attention (intermediate levels): r4 exp version, row-major writes.
// ---------------------------------------------------------------------------
template <int N>
__global__ __launch_bounds__(256) void gat_kernel(
    const float* __restrict__ x,  // (G,N,64)
    const float* __restrict__ w,  // [2][4][64] (src, dst)
    float* __restrict__ att) {    // (G,4,N,N)
    int g = blockIdx.x;
    const int tid = threadIdx.x;
    __shared__ float xlT[64][N + 1];  // [c][n]
    __shared__ float wl[512];
    __shared__ float a1s[4 * N], a2s[4 * N];
    __shared__ float mxs[4];
    __shared__ float mjs[4 * N], invs[4 * N];
    const float* xp = x + (size_t)g * N * 64;
    for (int idx = tid; idx < N * 64; idx += 256) {
        int n = idx >> 6, c = idx & 63;
        xlT[c][n] = xp[idx];
    }
    for (int idx = tid; idx < 512; idx += 256) wl[idx] = w[idx];
    __syncthreads();
    for (int idx = tid; idx < 8 * N; idx += 256) {
        int n = idx % N;
        int hh = (idx / N) & 3;
        int sd = idx / (4 * N);
        const float* wp = wl + sd * 256 + hh * 64;
        float acc = 0.f;
        #pragma unroll 8
        for (int c = 0; c < 64; ++c) acc += xlT[c][n] * wp[c];
        (sd == 0 ? a1s : a2s)[hh * N + n] = acc;
    }
    __syncthreads();
    if (tid < 4) {
        float m = -1e30f;
        for (int i = 0; i < N; ++i) m = fmaxf(m, a2s[tid * N + i]);
        mxs[tid] = m;
    }
    __syncthreads();
    for (int idx = tid; idx < 4 * N; idx += 256) {
        int hh = idx / N;
        float aj = a1s[idx];
        float mj = leaky(aj + mxs[hh]);   // leaky monotonic -> exact column max
        float ssum = 0.f;
        for (int i = 0; i < N; ++i) ssum += __expf(leaky(aj + a2s[hh * N + i]) - mj);
        mjs[idx] = mj;
        invs[idx] = 1.f / ssum;
    }
    __syncthreads();
    float* ob = att + (size_t)g * 4 * N * N;
    if constexpr ((N % 4) == 0) {
        constexpr int NF4 = N / 4;
        for (int idx = tid; idx < 4 * N * NF4; idx += 256) {
            int row = idx / NF4;           // h*N + i
            int j0 = (idx - row * NF4) * 4;
            int hh = row / N;
            float4 q1 = *(const float4*)&a1s[hh * N + j0];
            float4 qm = *(const float4*)&mjs[hh * N + j0];
            float4 qv = *(const float4*)&invs[hh * N + j0];
            float a2i = a2s[row];
            float a1v[4] = {q1.x, q1.y, q1.z, q1.w};
            float mv[4] = {qm.x, qm.y, qm.z, qm.w};
            float iv[4] = {qv.x, qv.y, qv.z, qv.w};
            float r[4];
            #pragma unroll
            for (int c = 0; c < 4; ++c) {
                float e = a1v[c] + a2i;
                e = e >= 0.f ? e : 0.2f * e;
                r[c] = __expf(e - mv[c]) * iv[c];
            }
            *(float4*)&ob[row * N + j0] = make_float4(r[0], r[1], r[2], r[3]);
        }
    } else {
        for (int idx = tid; idx < 4 * N * N; idx += 256) {
            int hh = idx / (N * N), rem = idx - hh * N * N;
            int i = rem / N, j = rem - i * N;
            float e = a1s[hh * N + j] + a2s[hh * N + i];
            e = e >= 0.f ? e : 0.2f * e;
            ob[idx] = __expf(e - mjs[hh * N + j]) * invs[hh * N + j];
        }
    }
}

// ---------------------------------------------------------------------------
// Diff-pool, register-tiled; GEMM1 uses 2x4 tiles when NP<=32 (thread util),
// GEMM2 per-element when KP<=12 (was 21-112 threads).
// ---------------------------------------------------------------------------
template <int N, int K, int KP>
__global__ __launch_bounds__(256, 3) void pool_kernel(
    const float* __restrict__ x,    // (G,N,64)
    const float* __restrict__ W1T,  // (64,64) [c][d]
    const float* __restrict__ b1,   // (64)
    const float* __restrict__ W2T,  // (64,KP) [d][k], pad cols zero
    const float* __restrict__ b2,   // (K)
    float* __restrict__ xo) {       // (G,K,64)
    constexpr int NP = (N + 3) & ~3;
    constexpr int LDN = NP + 1;
    __shared__ float xlT[64 * LDN];  // [c][n]
    __shared__ float yT[64 * LDN];   // [d][n]
    __shared__ float sT[KP * LDN];   // [k][n]
    const int g = blockIdx.x, tid = threadIdx.x;
    const float* xp = x + (size_t)g * N * 64;
    for (int i4 = tid; i4 < N * 16; i4 += 256) {
        int n = i4 >> 4, c0 = (i4 & 15) << 2;
        float4 v = ((const float4*)xp)[i4];
        xlT[(c0 + 0) * LDN + n] = v.x;
        xlT[(c0 + 1) * LDN + n] = v.y;
        xlT[(c0 + 2) * LDN + n] = v.z;
        xlT[(c0 + 3) * LDN + n] = v.w;
    }
    if constexpr (NP > N) {
        for (int i = tid; i < 64 * (NP - N); i += 256) {
            int c = i / (NP - N), n = N + i % (NP - N);
            xlT[c * LDN + n] = 0.f;
        }
    }
    __syncthreads();
    // ---- GEMM1: y = relu(x @ W1^T + b1) -> yT[d][n]
    if constexpr (NP <= 32) {
        constexpr int T1 = (NP / 2) * 16;
        if (tid < T1) {
            int d0 = (tid & 15) << 2, n0 = (tid >> 4) << 1;
            float acc[2][4] = {};
            #pragma unroll 4
            for (int c = 0; c < 64; ++c) {
                float4 w4 = *(const float4*)(W1T + c * 64 + d0);
                float wv[4] = {w4.x, w4.y, w4.z, w4.w};
                float x0 = xlT[c * LDN + n0];
                float x1 = xlT[c * LDN + n0 + 1];
                #pragma unroll
                for (int cc = 0; cc < 4; ++cc) {
                    acc[0][cc] += x0 * wv[cc];
                    acc[1][cc] += x1 * wv[cc];
                }
            }
            float4 b4 = *(const float4*)(b1 + d0);
            float bb[4] = {b4.x, b4.y, b4.z, b4.w};
            #pragma unroll
            for (int r = 0; r < 2; ++r)
                #pragma unroll
                for (int cc = 0; cc < 4; ++cc)
                    yT[(d0 + cc) * LDN + n0 + r] = fmaxf(acc[r][cc] + bb[cc], 0.f);
        }
    } else {
        constexpr int T1 = (NP / 4) * 16;
        if (tid < T1) {
            int d0 = (tid & 15) << 2, n0 = (tid >> 4) << 2;
            float acc[4][4] = {};
            #pragma unroll 4
            for (int c = 0; c < 64; ++c) {
                float4 w4 = *(const float4*)(W1T + c * 64 + d0);
                float wv[4] = {w4.x, w4.y, w4.z, w4.w};
                float xv[4];
                #pragma unroll
                for (int r = 0; r < 4; ++r) xv[r] = xlT[c * LDN + n0 + r];
                #pragma unroll
                for (int r = 0; r < 4; ++r)
                    #pragma unroll
                    for (int cc = 0; cc < 4; ++cc) acc[r][cc] += xv[r] * wv[cc];
            }
            float4 b4 = *(const float4*)(b1 + d0);
            float bb[4] = {b4.x, b4.y, b4.z, b4.w};
            #pragma unroll
            for (int r = 0; r < 4; ++r)
                #pragma unroll
                for (int cc = 0; cc < 4; ++cc)
                    yT[(d0 + cc) * LDN + n0 + r] = fmaxf(acc[r][cc] + bb[cc], 0.f);
        }
    }
    __syncthreads();
    // ---- GEMM2: s = y @ W2^T + b2 -> sT[k][n]
    if constexpr (KP <= 12) {
        for (int p = tid; p < N * KP; p += 256) {
            int n = p / KP, k = p - n * KP;
            float acc = 0.f;
            #pragma unroll 8
            for (int d = 0; d < 64; ++d)
                acc += yT[d * LDN + n] * W2T[d * KP + k];
            sT[k * LDN + n] = (k < K) ? (acc + b2[k]) : -1e30f;
        }
    } else {
        constexpr int KG4 = KP / 4;
        constexpr int T2 = (NP / 4) * KG4;
        if (tid < T2) {
            int k0 = (tid % KG4) << 2, n0 = (tid / KG4) << 2;
            float acc[4][4] = {};
            #pragma unroll 4
            for (int d = 0; d < 64; ++d) {
                float4 w4 = *(const float4*)(W2T + d * KP + k0);
                float wv[4] = {w4.x, w4.y, w4.z, w4.w};
                float yv[4];
                #pragma unroll
                for (int r = 0; r < 4; ++r) yv[r] = yT[d * LDN + n0 + r];
                #pragma unroll
                for (int r = 0; r < 4; ++r)
                    #pragma unroll
                    for (int cc = 0; cc < 4; ++cc) acc[r][cc] += yv[r] * wv[cc];
            }
            #pragma unroll
            for (int cc = 0; cc < 4; ++cc) {
                int k = k0 + cc;
                float bb = (k < K) ? b2[k] : 0.f;
                #pragma unroll
                for (int r = 0; r < 4; ++r)
                    sT[k * LDN + n0 + r] = (k < K) ? (acc[r][cc] + bb) : -1e30f;
            }
        }
    }
    __syncthreads();
    // ---- softmax over k per row n (rows < N only; pads unused)
    if (tid < N) {
        float m = -1e30f;
        #pragma unroll
        for (int k = 0; k < KP; ++k) m = fmaxf(m, sT[k * LDN + tid]);
        float sum = 0.f;
        float e[KP];
        #pragma unroll
        for (int k = 0; k < KP; ++k) { e[k] = __expf(sT[k * LDN + tid] - m); sum += e[k]; }
        float inv = 1.f / sum;
        #pragma unroll
        for (int k = 0; k < KP; ++k) sT[k * LDN + tid] = e[k] * inv;
    }
    __syncthreads();
    // ---- GEMM3: xo[k][c] = sum_n s[n][k] * x[n][c]
    constexpr int KG2 = (K + 1) / 2;
    constexpr int T3 = KG2 * 16;
    if (tid < T3) {
        int k0 = (tid % KG2) * 2, c0 = (tid / KG2) * 4;
        float acc0[4] = {}, acc1[4] = {};
        #pragma unroll 4
        for (int n = 0; n < N; ++n) {
            float sv0 = sT[k0 * LDN + n];
            float sv1 = sT[(k0 + 1) * LDN + n];
            float xv[4];
            #pragma unroll
            for (int j = 0; j < 4; ++j) xv[j] = xlT[(c0 + j) * LDN + n];
            #pragma unroll
            for (int j = 0; j < 4; ++j) { acc0[j] += sv0 * xv[j]; acc1[j] += sv1 * xv[j]; }
        }
        float* op = xo + (size_t)g * K * 64;
        *(float4*)&op[k0 * 64 + c0] = make_float4(acc0[0], acc0[1], acc0[2], acc0[3]);
        if (k0 + 1 < K)
            *(float4*)&op[(k0 + 1) * 64 + c0] = make_float4(acc1[0], acc1[1], acc1[2], acc1[3]);
    }
}

// ---------------------------------------------------------------------------
// Fused GAT0 + low-rank fuse, temporal. r12 version + bf16 t2T/r2l
// (LDS 29.2 -> 25.7 KB -> 6 blocks/CU). Block=(g,h) XCD-swizzled.
// ---------------------------------------------------------------------------
__global__ __launch_bounds__(256, 6) void gatfuse_t(
    const float* __restrict__ x,    // (1600,64,64)
    const float* __restrict__ w,    // [2][4][64]
    const float* __restrict__ A1g,  // (1600,4,32,32)
    const float* __restrict__ L1,   // (4,64,32)
    const float* __restrict__ R1,   // (4,32,64)
    const float* __restrict__ A2g,  // (1600,4,12,12)
    const float* __restrict__ L2,   // (4,64,12)
    const float* __restrict__ R2,   // (4,12,64)
    float* __restrict__ out)        // (1600,4,64,64)
{
    const int bid = blockIdx.x;
    const int g = (bid & 7) | ((bid >> 5) << 3);   // 4 heads of one g -> same XCD
    const int h = (bid >> 3) & 3;
    const int tid = threadIdx.x;
    __shared__ float t1T[32 * 64];            // [l][j]
    __shared__ float r1l[32 * 64];            // [l][m]
    __shared__ unsigned short t2Tb[12 * 64];  // bf16 [l][j]
    __shared__ unsigned short r2lb[12 * 64];  // bf16 [l][m]
    __shared__ float A1T[32 * 36];            // [l][k], padded
    __shared__ float A2T[12 * 13];            // [l][k]
    __shared__ float a1s[64], a2s[64], mjs[64], invs[64];

    // ---- phase 1: scores (waves 0-1) || stage A1,A2,R1,R2 (waves 2-3)
    if (tid < 128) {
        int t = tid & 63, sd = tid >> 6;
        const float4* xr = (const float4*)(x + (size_t)g * 4096 + t * 64);
        const float* wv = w + sd * 256 + h * 64;
        float acc = 0.f;
        #pragma unroll
        for (int q = 0; q < 16; ++q) {
            float4 xv = xr[q];
            acc += xv.x * wv[q * 4] + xv.y * wv[q * 4 + 1] +
                   xv.z * wv[q * 4 + 2] + xv.w * wv[q * 4 + 3];
        }
        (sd == 0 ? a1s : a2s)[t] = acc;
    } else {
        int u = tid - 128;
        const float* a1p = A1g + (size_t)(g * 4 + h) * 1024;
        #pragma unroll
        for (int q = 0; q < 8; ++q) {
            int idx = q * 128 + u;                 // = k*32 + l
            A1T[(idx & 31) * 36 + (idx >> 5)] = a1p[idx];
        }
        const float* a2p = A2g + (size_t)(g * 4 + h) * 144;
        for (int idx = u; idx < 144; idx += 128) {
            int k = idx / 12, l = idx - k * 12;
            A2T[l * 13 + k] = a2p[idx];
        }
        const float4* r1p = (const float4*)(R1 + h * 2048);
        #pragma unroll
        for (int q = 0; q < 4; ++q) ((float4*)r1l)[q * 128 + u] = r1p[q * 128 + u];
        const float* r2p = R2 + h * 768;
        for (int idx = u; idx < 768; idx += 128) r2lb[idx] = f2bf(r2p[idx]);
    }
    __syncthreads();

    // ---- phase 2: softmax column stats (threads 0-63)
    if (tid < 64) {
        float mx = a2s[0];
        for (int i = 1; i < 64; ++i) mx = fmaxf(mx, a2s[i]);
        float aj = a1s[tid];
        float mj = leaky(aj + mx);   // leaky monotonic -> exact column max
        float ssum = 0.f;
        for (int i = 0; i < 64; ++i) ssum += __expf(leaky(aj + a2s[i]) - mj);
        mjs[tid] = mj;
        invs[tid] = 1.f / ssum;
    }
    // ---- t1T[l][j] = sum_k L1[j][k] A1[k][l]  (thread: j=tid&63, 8 l's)
    {
        int j = tid & 63, l0 = (tid >> 6) * 8;
        float lj[32];
        const float4* lp = (const float4*)(L1 + (h * 64 + j) * 32);
        #pragma unroll
        for (int q = 0; q < 8; ++q) {
            float4 v = lp[q];
            lj[q * 4] = v.x; lj[q * 4 + 1] = v.y; lj[q * 4 + 2] = v.z; lj[q * 4 + 3] = v.w;
        }
        for (int l = l0; l < l0 + 8; ++l) {
            const float* ar = &A1T[l * 36];
            float acc = 0.f;
            #pragma unroll
            for (int k = 0; k < 32; k += 4) {
                float4 av = *(const float4*)&ar[k];
                acc += lj[k] * av.x + lj[k + 1] * av.y + lj[k + 2] * av.z + lj[k + 3] * av.w;
            }
            t1T[l * 64 + j] = acc;
        }
    }
    // ---- t2Tb[l][j] (bf16)  (thread: j=tid&63, 3 l's)
    {
        int j = tid & 63, lb = (tid >> 6) * 3;
        float lj2[12];
        const float* lp2 = L2 + (h * 64 + j) * 12;
        #pragma unroll
        for (int k = 0; k < 12; ++k) lj2[k] = lp2[k];
        for (int l = lb; l < lb + 3; ++l) {
            const float* ar = &A2T[l * 13];
            float acc = 0.f;
            #pragma unroll
            for (int k = 0; k < 12; ++k) acc += lj2[k] * ar[k];
            t2Tb[l * 64 + j] = f2bf(acc);
        }
    }
    __syncthreads();

    // ---- phase 3: 4x4 register-tiled output
    const int i0 = (tid >> 4) << 2, m0 = (tid & 15) << 2;
    float acc[4][4];
    {
        float4 q1 = *(const float4*)&a1s[m0];
        float4 qm = *(const float4*)&mjs[m0];
        float4 qv = *(const float4*)&invs[m0];
        float4 q2 = *(const float4*)&a2s[i0];
        float am[4] = {q1.x, q1.y, q1.z, q1.w};
        float mv[4] = {qm.x, qm.y, qm.z, qm.w};
        float iv[4] = {qv.x, qv.y, qv.z, qv.w};
        float ai[4] = {q2.x, q2.y, q2.z, q2.w};
        #pragma unroll
        for (int r = 0; r < 4; ++r)
            #pragma unroll
            for (int c = 0; c < 4; ++c) {
                float e = am[c] + ai[r];
                e = e >= 0.f ? e : 0.2f * e;
                acc[r][c] = __expf(e - mv[c]) * iv[c];
            }
    }
    #pragma unroll 8
    for (int l = 0; l < 32; ++l) {
        float4 t4 = *(const float4*)&t1T[l * 64 + i0];
        float4 r4 = *(const float4*)&r1l[l * 64 + m0];
        float tv[4] = {t4.x, t4.y, t4.z, t4.w};
        float rv[4] = {r4.x, r4.y, r4.z, r4.w};
        #pragma unroll
        for (int r = 0; r < 4; ++r)
            #pragma unroll
            for (int c = 0; c < 4; ++c) acc[r][c] += tv[r] * rv[c];
    }
    #pragma unroll 4
    for (int l = 0; l < 12; ++l) {
        uint2 tp = *(const uint2*)&t2Tb[l * 64 + i0];
        uint2 rp = *(const uint2*)&r2lb[l * 64 + m0];
        float tv[4] = {bflo(tp.x), bfhi(tp.x), bflo(tp.y), bfhi(tp.y)};
        float rv[4] = {bflo(rp.x), bfhi(rp.x), bflo(rp.y), bfhi(rp.y)};
        #pragma unroll
        for (int r = 0; r < 4; ++r)
            #pragma unroll
            for (int c = 0; c < 4; ++c) acc[r][c] += tv[r] * rv[c];
    }
    float* op = out + (size_t)(g * 4 + h) * 4096;
    #pragma unroll
    for (int r = 0; r < 4; ++r)
        nt_store4(&op[(i0 + r) * 64 + m0],
                  make_float4(acc[r][0], acc[r][1], acc[r][2], acc[r][3]));
}

// ---------------------------------------------------------------------------
// Fused GAT0 + fuse, spatial (r12 version, unchanged).
// ---------------------------------------------------------------------------
__global__ __launch_bounds__(256) void gatfuse_s(
    const float* __restrict__ x,    // (4096,25,64)
    const float* __restrict__ w,    // [2][4][64]
    const float* __restrict__ A1g,  // (4096,4,12,12)
    const float* __restrict__ L1,   // (4,25,12)
    const float* __restrict__ R1,   // (4,12,25)
    const float* __restrict__ A2g,  // (4096,4,5,5)
    const float* __restrict__ L2,   // (4,25,5)
    const float* __restrict__ R2,   // (4,5,25)
    float* __restrict__ out)        // (4096,4,25,25)
{
    const int g = blockIdx.x;
    const int tid = threadIdx.x;
    const int h = tid >> 6, t = tid & 63;
    __shared__ float xl[25 * 68];
    __shared__ float A1T[4][12 * 12];
    __shared__ float A2T[4][5 * 5];
    __shared__ float t1l[4][25 * 12];
    __shared__ float t2l[4][25 * 5];
    __shared__ float r1l[4][12 * 25];
    __shared__ float r2l[4][5 * 25];
    __shared__ float a1s[4][25], a2s[4][25], mjs[4][32], invs[4][32];

    const float* xp = x + (size_t)g * 1600;
    for (int idx = tid; idx < 1600; idx += 256) {
        int n = idx >> 6, c = idx & 63;
        xl[n * 68 + c] = xp[idx];
    }
    const float* a1p = A1g + (size_t)(g * 4 + h) * 144;
    for (int idx = t; idx < 144; idx += 64) {
        int k = idx / 12, l = idx - k * 12;
        A1T[h][l * 12 + k] = a1p[idx];
    }
    const float* a2p = A2g + (size_t)(g * 4 + h) * 25;
    if (t < 25) {
        int k = t / 5, l = t - 5 * (t / 5);
        A2T[h][l * 5 + k] = a2p[t];
    }
    for (int idx = t; idx < 300; idx += 64) r1l[h][idx] = R1[h * 300 + idx];
    for (int idx = t; idx < 125; idx += 64) r2l[h][idx] = R2[h * 125 + idx];
    __syncthreads();

    if (t < 25) {
        const float* ws_ = w + h * 64;
        const float* wd_ = w + 256 + h * 64;
        const float* xr = &xl[t * 68];
        float s1 = 0.f, s2 = 0.f;
        #pragma unroll
        for (int c = 0; c < 64; c += 4) {
            float4 xv = *(const float4*)&xr[c];
            s1 += xv.x * ws_[c] + xv.y * ws_[c + 1] + xv.z * ws_[c + 2] + xv.w * ws_[c + 3];
            s2 += xv.x * wd_[c] + xv.y * wd_[c + 1] + xv.z * wd_[c + 2] + xv.w * wd_[c + 3];
        }
        a1s[h][t] = s1;
        a2s[h][t] = s2;
    }
    __syncthreads();

    if (t < 25) {
        float mx = a2s[h][0];
        for (int i = 1; i < 25; ++i) mx = fmaxf(mx, a2s[h][i]);
        float aj = a1s[h][t];
        float mj = leaky(aj + mx);
        float ssum = 0.f;
        for (int i = 0; i < 25; ++i) ssum += __expf(leaky(aj + a2s[h][i]) - mj);
        mjs[h][t] = mj;
        invs[h][t] = 1.f / ssum;
        float lj[12];
        const float* lp = L1 + (h * 25 + t) * 12;
        #pragma unroll
        for (int k = 0; k < 12; ++k) lj[k] = lp[k];
        #pragma unroll
        for (int l = 0; l < 12; ++l) {
            const float* ar = &A1T[h][l * 12];
            float acc = 0.f;
            #pragma unroll
            for (int k = 0; k < 12; ++k) acc += lj[k] * ar[k];
            t1l[h][t * 12 + l] = acc;
        }
        float lj2[5];
        const float* lp2 = L2 + (h * 25 + t) * 5;
        #pragma unroll
        for (int k = 0; k < 5; ++k) lj2[k] = lp2[k];
        #pragma unroll
        for (int l = 0; l < 5; ++l) {
            const float* ar = &A2T[h][l * 5];
            float acc = 0.f;
            #pragma unroll
            for (int k = 0; k < 5; ++k) acc += lj2[k] * ar[k];
            t2l[h][t * 5 + l] = acc;
        }
    }
    __syncthreads();

    float* op = out + (size_t)(g * 4 + h) * 625;
    for (int idx = t; idx < 625; idx += 64) {
        int i = idx / 25, m = idx - i * 25;
        float e = a1s[h][m] + a2s[h][i];
        e = e >= 0.f ? e : 0.2f * e;
        float val = __expf(e - mjs[h][m]) * invs[h][m];
        const float* t1r = &t1l[h][i * 12];
        const float* r1c = &r1l[h][m];
        #pragma unroll
        for (int l = 0; l < 12; ++l) val += t1r[l] * r1c[l * 25];
        const float* t2r = &t2l[h][i * 5];
        const float* r2c = &r2l[h][m];
        #pragma unroll
        for (int l = 0; l < 5; ++l) val += t2r[l] * r2c[l * 25];
        __builtin_nontemporal_store(val, &op[idx]);
    }
}

// ---------------------------------------------------------------------------
extern "C" void kernel_launch(void* const* d_in, const int* in_sizes, int n_in,
                              void* d_out, int out_size, void* d_ws, size_t ws_size,
                              hipStream_t stream) {
    const float* src    = (const float*)d_in[0];
    const float* lin    = (const float*)d_in[1];
    const float* asrc   = (const float*)d_in[2];
    const float* adst   = (const float*)d_in[3];
    const float* sp0_W1 = (const float*)d_in[4];
    const float* sp0_b1 = (const float*)d_in[5];
    const float* sp0_W2 = (const float*)d_in[6];
    const float* sp0_b2 = (const float*)d_in[7];
    const float* sp1_W1 = (const float*)d_in[8];
    const float* sp1_b1 = (const float*)d_in[9];
    const float* sp1_W2 = (const float*)d_in[10];
    const float* sp1_b2 = (const float*)d_in[11];
    const float* tp0_W1 = (const float*)d_in[12];
    const float* tp0_b1 = (const float*)d_in[13];
    const float* tp0_W2 = (const float*)d_in[14];
    const float* tp0_b2 = (const float*)d_in[15];
    const float* tp1_W1 = (const float*)d_in[16];
    const float* tp1_b1 = (const float*)d_in[17];
    const float* tp1_W2 = (const float*)d_in[18];
    const float* tp1_b2 = (const float*)d_in[19];
    const float* sl0    = (const float*)d_in[20];
    const float* sr0    = (const float*)d_in[21];
    const float* sl1    = (const float*)d_in[22];
    const float* sr1    = (const float*)d_in[23];
    const float* tl0    = (const float*)d_in[24];
    const float* tr0    = (const float*)d_in[25];
    const float* tl1    = (const float*)d_in[26];
    const float* tr1    = (const float*)d_in[27];

    float* out_s = (float*)d_out;                 // (4096,4,25,25)
    float* out_t = out_s + 10240000;              // (1600,4,64,64)

    float* ws   = (float*)d_ws;
    float* wbuf = ws;                             // 3072 used (reserve 4096)
    float* wT   = ws + 4096;                      // 20480
    float* region = ws + 24576;

    float* sp0_W1T = wT;
    float* sp1_W1T = wT + 4096;
    float* tp0_W1T = wT + 8192;
    float* tp1_W1T = wT + 12288;
    float* sp0_W2T = wT + 16384;                  // 64x12
    float* sp1_W2T = wT + 17152;                  // 64x8
    float* tp0_W2T = wT + 17664;                  // 64x32
    float* tp1_W2T = wT + 19712;                  // 64x12

    // spatial aliases
    float* xs  = region;                          // 4096*25*64
    float* xs1 = xs + 6553600;                    // 4096*12*64
    float* xs2 = xs1 + 3145728;                   // 4096*5*64
    float* as1 = xs2 + 1310720;                   // 4096*4*12*12
    float* as2 = as1 + 2359296;                   // 4096*4*5*5
    // temporal aliases (region reused; branches sequential)
    float* xt  = region;                          // 1600*64*64
    float* xt1 = xt + 6553600;                    // 1600*32*64
    float* xt2 = xt1 + 3276800;                   // 1600*12*64
    float* at1 = xt2 + 1228800;                   // 1600*4*32*32
    float* at2 = at1 + 6553600;                   // 1600*4*12*12

    wprep_kernel<<<6, 256, 0, stream>>>(lin, asrc, adst, wbuf);
    wtrans_kernel<<<80, 256, 0, stream>>>(sp0_W1, sp1_W1, tp0_W1, tp1_W1,
                                          sp0_W2, sp1_W2, tp0_W2, tp1_W2, wT);

    // ---- spatial branch ----
    xs_kernel<<<4096, 256, 0, stream>>>(src, xs);
    pool_kernel<25, 12, 12><<<4096, 256, 0, stream>>>(xs, sp0_W1T, sp0_b1, sp0_W2T, sp0_b2, xs1);
    gat_kernel<12><<<4096, 256, 0, stream>>>(xs1, wbuf + 1 * 512, as1);
    pool_kernel<12, 5, 8><<<4096, 256, 0, stream>>>(xs1, sp1_W1T, sp1_b1, sp1_W2T, sp1_b2, xs2);
    gat_kernel<5><<<4096, 256, 0, stream>>>(xs2, wbuf + 2 * 512, as2);
    gatfuse_s<<<4096, 256, 0, stream>>>(xs, wbuf + 0 * 512, as1, sl0, sr0, as2, sl1, sr1, out_s);

    // ---- temporal branch ----
    xt_kernel<<<1600, 256, 0, stream>>>(src, xt);
    pool_kernel<64, 32, 32><<<1600, 256, 0, stream>>>(xt, tp0_W1T, tp0_b1, tp0_W2T, tp0_b2, xt1);
    gat_kernel<32><<<1600, 256, 0, stream>>>(xt1, wbuf + 4 * 512, at1);
    pool_kernel<32, 12, 12><<<1600, 256, 0, stream>>>(xt1, tp1_W1T, tp1_b1, tp1_W2T, tp1_b2, xt2);
    gat_kernel<12><<<1600, 256, 0, stream>>>(xt2, wbuf + 5 * 512, at2);
    gatfuse_t<<<6400, 256, 0, stream>>>(xt, wbuf + 3 * 512, at1, tl0, tr0, at2, tl1, tr1, out_t);
}

// Round 14
// 355.494 us; speedup vs baseline: 1.0369x; 1.0369x over previous
//
#include <hip/hip_runtime.h>

#define DEVINL __device__ __forceinline__

DEVINL float leaky(float v) { return v >= 0.f ? v : 0.2f * v; }

typedef float v4f __attribute__((ext_vector_type(4)));

DEVINL void nt_store4(float* p, float4 v) {
    v4f q = {v.x, v.y, v.z, v.w};
    __builtin_nontemporal_store(q, (v4f*)p);
}

// ---------------------------------------------------------------------------
// Precompute per-level head projection vectors.
// ---------------------------------------------------------------------------
__global__ void wprep_kernel(const float* __restrict__ lin,   // (6,64,64)
                             const float* __restrict__ asrc,  // (6,4,16)
                             const float* __restrict__ adst,  // (6,4,16)
                             float* __restrict__ w_out) {     // (6,2,4,64)
    int idx = blockIdx.x * blockDim.x + threadIdx.x;
    if (idx >= 6 * 4 * 64) return;
    int c = idx & 63;
    int h = (idx >> 6) & 3;
    int k = idx >> 8;
    const float* L = lin + k * 64 * 64;
    float s1 = 0.f, s2 = 0.f;
    for (int e = 0; e < 16; ++e) {
        float w = L[(h * 16 + e) * 64 + c];
        s1 += w * asrc[(k * 4 + h) * 16 + e];
        s2 += w * adst[(k * 4 + h) * 16 + e];
    }
    w_out[(k * 2 + 0) * 256 + h * 64 + c] = s1;
    w_out[(k * 2 + 1) * 256 + h * 64 + c] = s2;
}

// ---------------------------------------------------------------------------
// Transpose pool weights once.
// ---------------------------------------------------------------------------
__global__ void wtrans_kernel(const float* __restrict__ s0, const float* __restrict__ s1,
                              const float* __restrict__ t0, const float* __restrict__ t1,
                              const float* __restrict__ s0w2, const float* __restrict__ s1w2,
                              const float* __restrict__ t0w2, const float* __restrict__ t1w2,
                              float* __restrict__ o) {
    int idx = blockIdx.x * 256 + threadIdx.x;
    if (idx < 16384) {
        int m = idx >> 12, r = idx & 4095, c = r >> 6, d = r & 63;
        const float* src = (m == 0) ? s0 : (m == 1) ? s1 : (m == 2) ? t0 : t1;
        o[idx] = src[d * 64 + c];
    } else if (idx < 16384 + 768) {
        int j = idx - 16384, c = j / 12, k = j - 12 * c;
        o[idx] = s0w2[k * 64 + c];
    } else if (idx < 17152 + 512) {
        int j = idx - 17152, c = j >> 3, k = j & 7;
        o[idx] = (k < 5) ? s1w2[k * 64 + c] : 0.f;
    } else if (idx < 17664 + 2048) {
        int j = idx - 17664, c = j >> 5, k = j & 31;
        o[idx] = t0w2[k * 64 + c];
    } else if (idx < 19712 + 768) {
        int j = idx - 19712, c = j / 12, k = j - 12 * c;
        o[idx] = t1w2[k * 64 + c];
    }
}

// ---------------------------------------------------------------------------
// Transposes: src (B=64, C=64, T=64, J=25)
// ---------------------------------------------------------------------------
__global__ void xs_kernel(const float* __restrict__ src, float* __restrict__ xs) {
    int g = blockIdx.x;             // b*64 + t
    int b = g >> 6, t = g & 63;
    __shared__ float tile[64][26];  // [c][j]
    const float* sp = src + b * 102400 + t * 25;
    for (int idx = threadIdx.x; idx < 64 * 25; idx += blockDim.x) {
        int c = idx / 25, j = idx - c * 25;
        tile[c][j] = sp[c * 1600 + j];
    }
    __syncthreads();
    float* op = xs + g * 25 * 64;
    for (int idx = threadIdx.x; idx < 25 * 64; idx += blockDim.x) {
        int j = idx >> 6, c = idx & 63;
        op[idx] = tile[c][j];
    }
}

__global__ void xt_kernel(const float* __restrict__ src, float* __restrict__ xt) {
    int g = blockIdx.x;             // b*25 + j
    int b = g / 25, j = g - b * 25;
    __shared__ float tile[64][65];  // [c][t]
    const float* sp = src + b * 102400 + j;
    for (int idx = threadIdx.x; idx < 64 * 64; idx += blockDim.x) {
        int c = idx >> 6, t = idx & 63;
        tile[c][t] = sp[c * 1600 + t * 25];
    }
    __syncthreads();
    float* op = xt + g * 64 * 64;
    for (int idx = threadIdx.x; idx < 64 * 64; idx += blockDim.x) {
        int t = idx >> 6, c = idx & 63;
        op[idx] = tile[c][t];
    }
}

// ---------------------------------------------------------------------------
// GAT attention (intermediate levels): r4 exp version, row-major writes.
// ---------------------------------------------------------------------------
template <int N>
__global__ __launch_bounds__(256) void gat_kernel(
    const float* __restrict__ x,  // (G,N,64)
    const float* __restrict__ w,  // [2][4][64] (src, dst)
    float* __restrict__ att) {    // (G,4,N,N)
    int g = blockIdx.x;
    const int tid = threadIdx.x;
    __shared__ float xlT[64][N + 1];  // [c][n]
    __shared__ float wl[512];
    __shared__ float a1s[4 * N], a2s[4 * N];
    __shared__ float mxs[4];
    __shared__ float mjs[4 * N], invs[4 * N];
    const float* xp = x + (size_t)g * N * 64;
    for (int idx = tid; idx < N * 64; idx += 256) {
        int n = idx >> 6, c = idx & 63;
        xlT[c][n] = xp[idx];
    }
    for (int idx = tid; idx < 512; idx += 256) wl[idx] = w[idx];
    __syncthreads();
    for (int idx = tid; idx < 8 * N; idx += 256) {
        int n = idx % N;
        int hh = (idx / N) & 3;
        int sd = idx / (4 * N);
        const float* wp = wl + sd * 256 + hh * 64;
        float acc = 0.f;
        #pragma unroll 8
        for (int c = 0; c < 64; ++c) acc += xlT[c][n] * wp[c];
        (sd == 0 ? a1s : a2s)[hh * N + n] = acc;
    }
    __syncthreads();
    if (tid < 4) {
        float m = -1e30f;
        for (int i = 0; i < N; ++i) m = fmaxf(m, a2s[tid * N + i]);
        mxs[tid] = m;
    }
    __syncthreads();
    for (int idx = tid; idx < 4 * N; idx += 256) {
        int hh = idx / N;
        float aj = a1s[idx];
        float mj = leaky(aj + mxs[hh]);   // leaky monotonic -> exact column max
        float ssum = 0.f;
        for (int i = 0; i < N; ++i) ssum += __expf(leaky(aj + a2s[hh * N + i]) - mj);
        mjs[idx] = mj;
        invs[idx] = 1.f / ssum;
    }
    __syncthreads();
    float* ob = att + (size_t)g * 4 * N * N;
    if constexpr ((N % 4) == 0) {
        constexpr int NF4 = N / 4;
        for (int idx = tid; idx < 4 * N * NF4; idx += 256) {
            int row = idx / NF4;           // h*N + i
            int j0 = (idx - row * NF4) * 4;
            int hh = row / N;
            float4 q1 = *(const float4*)&a1s[hh * N + j0];
            float4 qm = *(const float4*)&mjs[hh * N + j0];
            float4 qv = *(const float4*)&invs[hh * N + j0];
            float a2i = a2s[row];
            float a1v[4] = {q1.x, q1.y, q1.z, q1.w};
            float mv[4] = {qm.x, qm.y, qm.z, qm.w};
            float iv[4] = {qv.x, qv.y, qv.z, qv.w};
            float r[4];
            #pragma unroll
            for (int c = 0; c < 4; ++c) {
                float e = a1v[c] + a2i;
                e = e >= 0.f ? e : 0.2f * e;
                r[c] = __expf(e - mv[c]) * iv[c];
            }
            *(float4*)&ob[row * N + j0] = make_float4(r[0], r[1], r[2], r[3]);
        }
    } else {
        for (int idx = tid; idx < 4 * N * N; idx += 256) {
            int hh = idx / (N * N), rem = idx - hh * N * N;
            int i = rem / N, j = rem - i * N;
            float e = a1s[hh * N + j] + a2s[hh * N + i];
            e = e >= 0.f ? e : 0.2f * e;
            ob[idx] = __expf(e - mjs[hh * N + j]) * invs[hh * N + j];
        }
    }
}

// ---------------------------------------------------------------------------
// Diff-pool, register-tiled (round-4 version).
// ---------------------------------------------------------------------------
template <int N, int K, int KP>
__global__ __launch_bounds__(256, 3) void pool_kernel(
    const float* __restrict__ x,    // (G,N,64)
    const float* __restrict__ W1T,  // (64,64) [c][d]
    const float* __restrict__ b1,   // (64)
    const float* __restrict__ W2T,  // (64,KP) [d][k], pad cols zero
    const float* __restrict__ b2,   // (K)
    float* __restrict__ xo) {       // (G,K,64)
    constexpr int NP = (N + 3) & ~3;
    constexpr int LDN = NP + 1;
    __shared__ float xlT[64 * LDN];  // [c][n]
    __shared__ float yT[64 * LDN];   // [d][n]
    __shared__ float sT[KP * LDN];   // [k][n]
    const int g = blockIdx.x, tid = threadIdx.x;
    const float* xp = x + (size_t)g * N * 64;
    for (int i4 = tid; i4 < N * 16; i4 += 256) {
        int n = i4 >> 4, c0 = (i4 & 15) << 2;
        float4 v = ((const float4*)xp)[i4];
        xlT[(c0 + 0) * LDN + n] = v.x;
        xlT[(c0 + 1) * LDN + n] = v.y;
        xlT[(c0 + 2) * LDN + n] = v.z;
        xlT[(c0 + 3) * LDN + n] = v.w;
    }
    if constexpr (NP > N) {
        for (int i = tid; i < 64 * (NP - N); i += 256) {
            int c = i / (NP - N), n = N + i % (NP - N);
            xlT[c * LDN + n] = 0.f;
        }
    }
    __syncthreads();
    constexpr int T1 = (NP / 4) * 16;
    if (tid < T1) {
        int d0 = (tid & 15) << 2, n0 = (tid >> 4) << 2;
        float acc[4][4] = {};
        #pragma unroll 4
        for (int c = 0; c < 64; ++c) {
            float4 w4 = *(const float4*)(W1T + c * 64 + d0);
            float wv[4] = {w4.x, w4.y, w4.z, w4.w};
            float xv[4];
            #pragma unroll
            for (int r = 0; r < 4; ++r) xv[r] = xlT[c * LDN + n0 + r];
            #pragma unroll
            for (int r = 0; r < 4; ++r)
                #pragma unroll
                for (int cc = 0; cc < 4; ++cc) acc[r][cc] += xv[r] * wv[cc];
        }
        float4 b4 = *(const float4*)(b1 + d0);
        float bb[4] = {b4.x, b4.y, b4.z, b4.w};
        #pragma unroll
        for (int r = 0; r < 4; ++r)
            #pragma unroll
            for (int cc = 0; cc < 4; ++cc)
                yT[(d0 + cc) * LDN + n0 + r] = fmaxf(acc[r][cc] + bb[cc], 0.f);
    }
    __syncthreads();
    constexpr int KG4 = KP / 4;
    constexpr int T2 = (NP / 4) * KG4;
    if (tid < T2) {
        int k0 = (tid % KG4) << 2, n0 = (tid / KG4) << 2;
        float acc[4][4] = {};
        #pragma unroll 4
        for (int d = 0; d < 64; ++d) {
            float4 w4 = *(const float4*)(W2T + d * KP + k0);
            float wv[4] = {w4.x, w4.y, w4.z, w4.w};
            float yv[4];
            #pragma unroll
            for (int r = 0; r < 4; ++r) yv[r] = yT[d * LDN + n0 + r];
            #pragma unroll
            for (int r = 0; r < 4; ++r)
                #pragma unroll
                for (int cc = 0; cc < 4; ++cc) acc[r][cc] += yv[r] * wv[cc];
        }
        #pragma unroll
        for (int cc = 0; cc < 4; ++cc) {
            int k = k0 + cc;
            float bb = (k < K) ? b2[k] : 0.f;
            #pragma unroll
            for (int r = 0; r < 4; ++r)
                sT[k * LDN + n0 + r] = (k < K) ? (acc[r][cc] + bb) : -1e30f;
        }
    }
    __syncthreads();
    if (tid < NP) {
        float m = -1e30f;
        #pragma unroll
        for (int k = 0; k < KP; ++k) m = fmaxf(m, sT[k * LDN + tid]);
        float sum = 0.f;
        float e[KP];
        #pragma unroll
        for (int k = 0; k < KP; ++k) { e[k] = __expf(sT[k * LDN + tid] - m); sum += e[k]; }
        float inv = 1.f / sum;
        #pragma unroll
        for (int k = 0; k < KP; ++k) sT[k * LDN + tid] = e[k] * inv;
    }
    __syncthreads();
    constexpr int KG2 = (K + 1) / 2;
    constexpr int T3 = KG2 * 16;
    if (tid < T3) {
        int k0 = (tid % KG2) * 2, c0 = (tid / KG2) * 4;
        float acc0[4] = {}, acc1[4] = {};
        #pragma unroll 4
        for (int n = 0; n < N; ++n) {
            float sv0 = sT[k0 * LDN + n];
            float sv1 = sT[(k0 + 1) * LDN + n];
            float xv[4];
            #pragma unroll
            for (int j = 0; j < 4; ++j) xv[j] = xlT[(c0 + j) * LDN + n];
            #pragma unroll
            for (int j = 0; j < 4; ++j) { acc0[j] += sv0 * xv[j]; acc1[j] += sv1 * xv[j]; }
        }
        float* op = xo + (size_t)g * K * 64;
        *(float4*)&op[k0 * 64 + c0] = make_float4(acc0[0], acc0[1], acc0[2], acc0[3]);
        if (k0 + 1 < K)
            *(float4*)&op[(k0 + 1) * 64 + c0] = make_float4(acc1[0], acc1[1], acc1[2], acc1[3]);
    }
}

// ---------------------------------------------------------------------------
// Fused GAT0 + low-rank fuse, temporal (r12: padded A1T + NT stores).
// Block = (g,h) XCD-swizzled, 256 threads, 4x4 register tile.
// ---------------------------------------------------------------------------
__global__ __launch_bounds__(256, 5) void gatfuse_t(
    const float* __restrict__ x,    // (1600,64,64)
    const float* __restrict__ w,    // [2][4][64]
    const float* __restrict__ A1g,  // (1600,4,32,32)
    const float* __restrict__ L1,   // (4,64,32)
    const float* __restrict__ R1,   // (4,32,64)
    const float* __restrict__ A2g,  // (1600,4,12,12)
    const float* __restrict__ L2,   // (4,64,12)
    const float* __restrict__ R2,   // (4,12,64)
    float* __restrict__ out)        // (1600,4,64,64)
{
    const int bid = blockIdx.x;
    const int g = (bid & 7) | ((bid >> 5) << 3);   // 4 heads of one g -> same XCD
    const int h = (bid >> 3) & 3;
    const int tid = threadIdx.x;
    __shared__ float t1T[32 * 64];   // [l][j]
    __shared__ float r1l[32 * 64];   // [l][m]
    __shared__ float t2T[12 * 64];
    __shared__ float r2l[12 * 64];
    __shared__ float A1T[32 * 36];   // [l][k], padded (conflict fix)
    __shared__ float A2T[12 * 13];   // [l][k]
    __shared__ float a1s[64], a2s[64], mjs[64], invs[64];

    // ---- phase 1: scores (waves 0-1) || stage A1,A2,R1,R2 (waves 2-3)
    if (tid < 128) {
        int t = tid & 63, sd = tid >> 6;
        const float4* xr = (const float4*)(x + (size_t)g * 4096 + t * 64);
        const float* wv = w + sd * 256 + h * 64;
        float acc = 0.f;
        #pragma unroll
        for (int q = 0; q < 16; ++q) {
            float4 xv = xr[q];
            acc += xv.x * wv[q * 4] + xv.y * wv[q * 4 + 1] +
                   xv.z * wv[q * 4 + 2] + xv.w * wv[q * 4 + 3];
        }
        (sd == 0 ? a1s : a2s)[t] = acc;
    } else {
        int u = tid - 128;
        const float* a1p = A1g + (size_t)(g * 4 + h) * 1024;
        #pragma unroll
        for (int q = 0; q < 8; ++q) {
            int idx = q * 128 + u;                 // = k*32 + l
            A1T[(idx & 31) * 36 + (idx >> 5)] = a1p[idx];
        }
        const float* a2p = A2g + (size_t)(g * 4 + h) * 144;
        for (int idx = u; idx < 144; idx += 128) {
            int k = idx / 12, l = idx - k * 12;
            A2T[l * 13 + k] = a2p[idx];
        }
        const float4* r1p = (const float4*)(R1 + h * 2048);
        #pragma unroll
        for (int q = 0; q < 4; ++q) ((float4*)r1l)[q * 128 + u] = r1p[q * 128 + u];
        const float4* r2p = (const float4*)(R2 + h * 768);
        for (int idx = u; idx < 192; idx += 128) ((float4*)r2l)[idx] = r2p[idx];
    }
    __syncthreads();

    // ---- phase 2: softmax column stats (threads 0-63)
    if (tid < 64) {
        float mx = a2s[0];
        for (int i = 1; i < 64; ++i) mx = fmaxf(mx, a2s[i]);
        float aj = a1s[tid];
        float mj = leaky(aj + mx);   // leaky monotonic -> exact column max
        float ssum = 0.f;
        for (int i = 0; i < 64; ++i) ssum += __expf(leaky(aj + a2s[i]) - mj);
        mjs[tid] = mj;
        invs[tid] = 1.f / ssum;
    }
    // ---- t1T[l][j] = sum_k L1[j][k] A1[k][l]  (thread: j=tid&63, 8 l's)
    {
        int j = tid & 63, l0 = (tid >> 6) * 8;
        float lj[32];
        const float4* lp = (const float4*)(L1 + (h * 64 + j) * 32);
        #pragma unroll
        for (int q = 0; q < 8; ++q) {
            float4 v = lp[q];
            lj[q * 4] = v.x; lj[q * 4 + 1] = v.y; lj[q * 4 + 2] = v.z; lj[q * 4 + 3] = v.w;
        }
        for (int l = l0; l < l0 + 8; ++l) {
            const float* ar = &A1T[l * 36];
            float acc = 0.f;
            #pragma unroll
            for (int k = 0; k < 32; k += 4) {
                float4 av = *(const float4*)&ar[k];
                acc += lj[k] * av.x + lj[k + 1] * av.y + lj[k + 2] * av.z + lj[k + 3] * av.w;
            }
            t1T[l * 64 + j] = acc;
        }
    }
    // ---- t2T[l][j]  (thread: j=tid&63, 3 l's)
    {
        int j = tid & 63, lb = (tid >> 6) * 3;
        float lj2[12];
        const float* lp2 = L2 + (h * 64 + j) * 12;
        #pragma unroll
        for (int k = 0; k < 12; ++k) lj2[k] = lp2[k];
        for (int l = lb; l < lb + 3; ++l) {
            const float* ar = &A2T[l * 13];
            float acc = 0.f;
            #pragma unroll
            for (int k = 0; k < 12; ++k) acc += lj2[k] * ar[k];
            t2T[l * 64 + j] = acc;
        }
    }
    __syncthreads();

    // ---- phase 3: 4x4 register-tiled output
    const int i0 = (tid >> 4) << 2, m0 = (tid & 15) << 2;
    float acc[4][4];
    {
        float4 q1 = *(const float4*)&a1s[m0];
        float4 qm = *(const float4*)&mjs[m0];
        float4 qv = *(const float4*)&invs[m0];
        float4 q2 = *(const float4*)&a2s[i0];
        float am[4] = {q1.x, q1.y, q1.z, q1.w};
        float mv[4] = {qm.x, qm.y, qm.z, qm.w};
        float iv[4] = {qv.x, qv.y, qv.z, qv.w};
        float ai[4] = {q2.x, q2.y, q2.z, q2.w};
        #pragma unroll
        for (int r = 0; r < 4; ++r)
            #pragma unroll
            for (int c = 0; c < 4; ++c) {
                float e = am[c] + ai[r];
                e = e >= 0.f ? e : 0.2f * e;
                acc[r][c] = __expf(e - mv[c]) * iv[c];
            }
    }
    #pragma unroll 8
    for (int l = 0; l < 32; ++l) {
        float4 t4 = *(const float4*)&t1T[l * 64 + i0];
        float4 r4 = *(const float4*)&r1l[l * 64 + m0];
        float tv[4] = {t4.x, t4.y, t4.z, t4.w};
        float rv[4] = {r4.x, r4.y, r4.z, r4.w};
        #pragma unroll
        for (int r = 0; r < 4; ++r)
            #pragma unroll
            for (int c = 0; c < 4; ++c) acc[r][c] += tv[r] * rv[c];
    }
    #pragma unroll 4
    for (int l = 0; l < 12; ++l) {
        float4 t4 = *(const float4*)&t2T[l * 64 + i0];
        float4 r4 = *(const float4*)&r2l[l * 64 + m0];
        float tv[4] = {t4.x, t4.y, t4.z, t4.w};
        float rv[4] = {r4.x, r4.y, r4.z, r4.w};
        #pragma unroll
        for (int r = 0; r < 4; ++r)
            #pragma unroll
            for (int c = 0; c < 4; ++c) acc[r][c] += tv[r] * rv[c];
    }
    float* op = out + (size_t)(g * 4 + h) * 4096;
    #pragma unroll
    for (int r = 0; r < 4; ++r)
        nt_store4(&op[(i0 + r) * 64 + m0],
                  make_float4(acc[r][0], acc[r][1], acc[r][2], acc[r][3]));
}

// ---------------------------------------------------------------------------
// Fused GAT0 + fuse, spatial (r12 version).
// ---------------------------------------------------------------------------
__global__ __launch_bounds__(256) void gatfuse_s(
    const float* __restrict__ x,    // (4096,25,64)
    const float* __restrict__ w,    // [2][4][64]
    const float* __restrict__ A1g,  // (4096,4,12,12)
    const float* __restrict__ L1,   // (4,25,12)
    const float* __restrict__ R1,   // (4,12,25)
    const float* __restrict__ A2g,  // (4096,4,5,5)
    const float* __restrict__ L2,   // (4,25,5)
    const float* __restrict__ R2,   // (4,5,25)
    float* __restrict__ out)        // (4096,4,25,25)
{
    const int g = blockIdx.x;
    const int tid = threadIdx.x;
    const int h = tid >> 6, t = tid & 63;
    __shared__ float xl[25 * 68];
    __shared__ float A1T[4][12 * 12];
    __shared__ float A2T[4][5 * 5];
    __shared__ float t1l[4][25 * 12];
    __shared__ float t2l[4][25 * 5];
    __shared__ float r1l[4][12 * 25];
    __shared__ float r2l[4][5 * 25];
    __shared__ float a1s[4][25], a2s[4][25], mjs[4][32], invs[4][32];

    const float* xp = x + (size_t)g * 1600;
    for (int idx = tid; idx < 1600; idx += 256) {
        int n = idx >> 6, c = idx & 63;
        xl[n * 68 + c] = xp[idx];
    }
    const float* a1p = A1g + (size_t)(g * 4 + h) * 144;
    for (int idx = t; idx < 144; idx += 64) {
        int k = idx / 12, l = idx - k * 12;
        A1T[h][l * 12 + k] = a1p[idx];
    }
    const float* a2p = A2g + (size_t)(g * 4 + h) * 25;
    if (t < 25) {
        int k = t / 5, l = t - 5 * (t / 5);
        A2T[h][l * 5 + k] = a2p[t];
    }
    for (int idx = t; idx < 300; idx += 64) r1l[h][idx] = R1[h * 300 + idx];
    for (int idx = t; idx < 125; idx += 64) r2l[h][idx] = R2[h * 125 + idx];
    __syncthreads();

    if (t < 25) {
        const float* ws_ = w + h * 64;
        const float* wd_ = w + 256 + h * 64;
        const float* xr = &xl[t * 68];
        float s1 = 0.f, s2 = 0.f;
        #pragma unroll
        for (int c = 0; c < 64; c += 4) {
            float4 xv = *(const float4*)&xr[c];
            s1 += xv.x * ws_[c] + xv.y * ws_[c + 1] + xv.z * ws_[c + 2] + xv.w * ws_[c + 3];
            s2 += xv.x * wd_[c] + xv.y * wd_[c + 1] + xv.z * wd_[c + 2] + xv.w * wd_[c + 3];
        }
        a1s[h][t] = s1;
        a2s[h][t] = s2;
    }
    __syncthreads();

    if (t < 25) {
        float mx = a2s[h][0];
        for (int i = 1; i < 25; ++i) mx = fmaxf(mx, a2s[h][i]);
        float aj = a1s[h][t];
        float mj = leaky(aj + mx);
        float ssum = 0.f;
        for (int i = 0; i < 25; ++i) ssum += __expf(leaky(aj + a2s[h][i]) - mj);
        mjs[h][t] = mj;
        invs[h][t] = 1.f / ssum;
        float lj[12];
        const float* lp = L1 + (h * 25 + t) * 12;
        #pragma unroll
        for (int k = 0; k < 12; ++k) lj[k] = lp[k];
        #pragma unroll
        for (int l = 0; l < 12; ++l) {
            const float* ar = &A1T[h][l * 12];
            float acc = 0.f;
            #pragma unroll
            for (int k = 0; k < 12; ++k) acc += lj[k] * ar[k];
            t1l[h][t * 12 + l] = acc;
        }
        float lj2[5];
        const float* lp2 = L2 + (h * 25 + t) * 5;
        #pragma unroll
        for (int k = 0; k < 5; ++k) lj2[k] = lp2[k];
        #pragma unroll
        for (int l = 0; l < 5; ++l) {
            const float* ar = &A2T[h][l * 5];
            float acc = 0.f;
            #pragma unroll
            for (int k = 0; k < 5; ++k) acc += lj2[k] * ar[k];
            t2l[h][t * 5 + l] = acc;
        }
    }
    __syncthreads();

    float* op = out + (size_t)(g * 4 + h) * 625;
    for (int idx = t; idx < 625; idx += 64) {
        int i = idx / 25, m = idx - i * 25;
        float e = a1s[h][m] + a2s[h][i];
        e = e >= 0.f ? e : 0.2f * e;
        float val = __expf(e - mjs[h][m]) * invs[h][m];
        const float* t1r = &t1l[h][i * 12];
        const float* r1c = &r1l[h][m];
        #pragma unroll
        for (int l = 0; l < 12; ++l) val += t1r[l] * r1c[l * 25];
        const float* t2r = &t2l[h][i * 5];
        const float* r2c = &r2l[h][m];
        #pragma unroll
        for (int l = 0; l < 5; ++l) val += t2r[l] * r2c[l * 25];
        __builtin_nontemporal_store(val, &op[idx]);
    }
}

// ---------------------------------------------------------------------------
extern "C" void kernel_launch(void* const* d_in, const int* in_sizes, int n_in,
                              void* d_out, int out_size, void* d_ws, size_t ws_size,
                              hipStream_t stream) {
    const float* src    = (const float*)d_in[0];
    const float* lin    = (const float*)d_in[1];
    const float* asrc   = (const float*)d_in[2];
    const float* adst   = (const float*)d_in[3];
    const float* sp0_W1 = (const float*)d_in[4];
    const float* sp0_b1 = (const float*)d_in[5];
    const float* sp0_W2 = (const float*)d_in[6];
    const float* sp0_b2 = (const float*)d_in[7];
    const float* sp1_W1 = (const float*)d_in[8];
    const float* sp1_b1 = (const float*)d_in[9];
    const float* sp1_W2 = (const float*)d_in[10];
    const float* sp1_b2 = (const float*)d_in[11];
    const float* tp0_W1 = (const float*)d_in[12];
    const float* tp0_b1 = (const float*)d_in[13];
    const float* tp0_W2 = (const float*)d_in[14];
    const float* tp0_b2 = (const float*)d_in[15];
    const float* tp1_W1 = (const float*)d_in[16];
    const float* tp1_b1 = (const float*)d_in[17];
    const float* tp1_W2 = (const float*)d_in[18];
    const float* tp1_b2 = (const float*)d_in[19];
    const float* sl0    = (const float*)d_in[20];
    const float* sr0    = (const float*)d_in[21];
    const float* sl1    = (const float*)d_in[22];
    const float* sr1    = (const float*)d_in[23];
    const float* tl0    = (const float*)d_in[24];
    const float* tr0    = (const float*)d_in[25];
    const float* tl1    = (const float*)d_in[26];
    const float* tr1    = (const float*)d_in[27];

    float* out_s = (float*)d_out;                 // (4096,4,25,25)
    float* out_t = out_s + 10240000;              // (1600,4,64,64)

    float* ws   = (float*)d_ws;
    float* wbuf = ws;                             // 3072 used (reserve 4096)
    float* wT   = ws + 4096;                      // 20480
    float* region = ws + 24576;

    float* sp0_W1T = wT;
    float* sp1_W1T = wT + 4096;
    float* tp0_W1T = wT + 8192;
    float* tp1_W1T = wT + 12288;
    float* sp0_W2T = wT + 16384;                  // 64x12
    float* sp1_W2T = wT + 17152;                  // 64x8
    float* tp0_W2T = wT + 17664;                  // 64x32
    float* tp1_W2T = wT + 19712;                  // 64x12

    // spatial aliases
    float* xs  = region;                          // 4096*25*64
    float* xs1 = xs + 6553600;                    // 4096*12*64
    float* xs2 = xs1 + 3145728;                   // 4096*5*64
    float* as1 = xs2 + 1310720;                   // 4096*4*12*12
    float* as2 = as1 + 2359296;                   // 4096*4*5*5
    // temporal aliases (region reused; branches sequential)
    float* xt  = region;                          // 1600*64*64
    float* xt1 = xt + 6553600;                    // 1600*32*64
    float* xt2 = xt1 + 3276800;                   // 1600*12*64
    float* at1 = xt2 + 1228800;                   // 1600*4*32*32
    float* at2 = at1 + 6553600;                   // 1600*4*12*12

    wprep_kernel<<<6, 256, 0, stream>>>(lin, asrc, adst, wbuf);
    wtrans_kernel<<<80, 256, 0, stream>>>(sp0_W1, sp1_W1, tp0_W1, tp1_W1,
                                          sp0_W2, sp1_W2, tp0_W2, tp1_W2, wT);

    // ---- spatial branch ----
    xs_kernel<<<4096, 256, 0, stream>>>(src, xs);
    pool_kernel<25, 12, 12><<<4096, 256, 0, stream>>>(xs, sp0_W1T, sp0_b1, sp0_W2T, sp0_b2, xs1);
    gat_kernel<12><<<4096, 256, 0, stream>>>(xs1, wbuf + 1 * 512, as1);
    pool_kernel<12, 5, 8><<<4096, 256, 0, stream>>>(xs1, sp1_W1T, sp1_b1, sp1_W2T, sp1_b2, xs2);
    gat_kernel<5><<<4096, 256, 0, stream>>>(xs2, wbuf + 2 * 512, as2);
    gatfuse_s<<<4096, 256, 0, stream>>>(xs, wbuf + 0 * 512, as1, sl0, sr0, as2, sl1, sr1, out_s);

    // ---- temporal branch ----
    xt_kernel<<<1600, 256, 0, stream>>>(src, xt);
    pool_kernel<64, 32, 32><<<1600, 256, 0, stream>>>(xt, tp0_W1T, tp0_b1, tp0_W2T, tp0_b2, xt1);
    gat_kernel<32><<<1600, 256, 0, stream>>>(xt1, wbuf + 4 * 512, at1);
    pool_kernel<32, 12, 12><<<1600, 256, 0, stream>>>(xt1, tp1_W1T, tp1_b1, tp1_W2T, tp1_b2, xt2);
    gat_kernel<12><<<1600, 256, 0, stream>>>(xt2, wbuf + 5 * 512, at2);
    gatfuse_t<<<6400, 256, 0, stream>>>(xt, wbuf + 3 * 512, at1, tl0, tr0, at2, tl1, tr1, out_t);
}